// Round 7
// baseline (1590.147 us; speedup 1.0000x reference)
//
#include <hip/hip_runtime.h>
#include <hip/hip_bf16.h>

// FFT-tiled conv: B=8, IMG=256, CIN=COUT=64, TILE=64, FFT=68, PAD=2.
// Frequency-domain per-tile conv via DFT-as-matmul, Hermitian half-spectrum
// (k2 in [0,35)), direct overlap-add via atomics. All fp32.
//
// Layouts (per 16-tile chunk slot of CHS floats):
//   Y  [nl][k2][r][i][c]      in bufA     ((nl*35+k2)*64+r)*128
//   X  [nl][k1][k2][i][c]     in bufB     ((nl*68+k1)*35+k2)*128
//   K_t[bin][i][o][c]         78 MB, one-time (bin = k1*35+k2)
//   O  [nl][k2][k1][o][c]     in bufA     ((nl*35+k2)*68+k1)*128
//   Z  [nl][p][k2][o][c]      in bufB     ((nl*68+p)*35+k2)*128

#define KH   35
#define CHS  4874240ull                       // floats per chunk slot
#define KT_FLOATS (68ull * KH * 64 * 64 * 2)  // 19,496,960

__global__ void k_twiddle(float* ws) {
    const float TWO_PI = 6.28318530717958647692f;
    int t = threadIdx.x;
    float* Wf = ws;
    for (int e = t; e < 68 * 64; e += 256) {
        int k = e >> 6, m = e & 63;
        int ph = (k * (m + 2)) % 68;
        float a = TWO_PI * (float)ph / 68.0f;
        Wf[2 * e]     = cosf(a);
        Wf[2 * e + 1] = -sinf(a);
    }
    float* Wi = ws + 8704;
    for (int e = t; e < 68 * 68; e += 256) {
        int p = e / 68, k = e % 68;
        int ph = (p * k) % 68;
        float a = TWO_PI * (float)ph / 68.0f;
        Wi[2 * e]     = cosf(a) / 68.0f;
        Wi[2 * e + 1] = sinf(a) / 68.0f;
    }
    float* Wg = ws + 17952;
    for (int e = t; e < 68 * KH; e += 256) {
        int q = e / KH, k2 = e % KH;
        int ph = (q * k2) % 68;
        float a = TWO_PI * (float)ph / 68.0f;
        float alpha = (k2 == 0 || k2 == 34) ? 1.0f : 2.0f;
        Wg[2 * e]     = alpha * cosf(a) / 68.0f;
        Wg[2 * e + 1] = alpha * sinf(a) / 68.0f;
    }
}

__global__ void k_zero(float* out, int n) {
    int idx = blockIdx.x * 256 + threadIdx.x;
    float4* o4 = (float4*)out;
    for (int i = idx; i < n / 4; i += gridDim.x * 256) o4[i] = make_float4(0, 0, 0, 0);
}

// ---------- one-time kernel-spectrum transpose: K_t[bin][i][o][c] ----------
__global__ void k_ktrans(const float* __restrict__ kr, const float* __restrict__ ki,
                         float* __restrict__ Kt) {
    __shared__ float tr[64 * 37];
    __shared__ float ti[64 * 37];
    int k1 = blockIdx.x >> 6, i = blockIdx.x & 63;
    int t = threadIdx.x;
    for (int e = t; e < 64 * KH; e += 256) {
        int o = e / KH, k2 = e % KH;
        size_t src = ((size_t)(o * 64 + i) * 68 + k1) * 68 + k2;
        tr[o * 37 + k2] = kr[src];
        ti[o * 37 + k2] = ki[src];
    }
    __syncthreads();
    for (int e = t; e < KH * 64; e += 256) {
        int k2 = e >> 6, o = e & 63;
        size_t dst = ((size_t)(k1 * KH + k2)) * 8192 + (size_t)i * 128 + o * 2;
        Kt[dst]     = tr[o * 37 + k2];
        Kt[dst + 1] = ti[o * 37 + k2];
    }
}

// ---------------- stage 1: row DFT ----------------
// Y[nl][k2][r][i] = sum_c x[b, tr*64+r, tc*64+c, i] * Wf[k2][c]
__global__ void k_fwd_row(const float* __restrict__ x, const float* __restrict__ Wf,
                          float* __restrict__ Y, int c0) {
    __shared__ float xr[64 * 64];        // [c][i]
    __shared__ float wf[KH * 64 * 2];    // [k2][c]
    __shared__ float yout[KH * 128];     // [k2][i][c]
    int lc = blockIdx.x >> 10;
    int rem = blockIdx.x & 1023;
    int nl = rem >> 6, r = rem & 63;
    int n = (c0 + lc) * 16 + nl;
    int b = n >> 4, tr = (n >> 2) & 3, tc = n & 3;
    const float* src = x + (((size_t)(b * 256 + tr * 64 + r)) * 256 + tc * 64) * 64;
    int t = threadIdx.x;
    const float4* src4 = (const float4*)src;
    float4* xr4 = (float4*)xr;
    for (int e = t; e < 1024; e += 256) xr4[e] = src4[e];
    for (int e = t; e < KH * 64 * 2; e += 256) wf[e] = Wf[e];
    __syncthreads();
    int i = t & 63, kg = t >> 6;
    for (int k2 = kg; k2 < KH; k2 += 4) {
        float ar = 0.f, ai = 0.f;
        const float* w = wf + k2 * 128;
        for (int c = 0; c < 64; ++c) {
            float v = xr[(c << 6) | i];
            ar += v * w[2 * c];
            ai += v * w[2 * c + 1];
        }
        yout[(k2 << 7) + 2 * i]     = ar;
        yout[(k2 << 7) + 2 * i + 1] = ai;
    }
    __syncthreads();
    // copy out: per k2, 128-float run at ((nl*35+k2)*64+r)*128
    float* Yc = Y + (size_t)lc * CHS;
    const float4* ys4 = (const float4*)yout;
    for (int e = t; e < KH * 32; e += 256) {
        int k2 = e >> 5, f = e & 31;
        ((float4*)(Yc + ((size_t)(nl * KH + k2) * 64 + r) * 128))[f] = ys4[e];
    }
}

// ---------------- stage 2: column DFT (per-(nl,k2) GEMM) ----------------
// X[nl][k1][k2][i] = sum_r Wf[k1][r] * Y[nl][k2][r][i]
__global__ __launch_bounds__(512) void k_fwd_col(
        const float* __restrict__ Y, const float* __restrict__ Wf,
        float* __restrict__ X) {
    __shared__ float yl[64 * 128];       // 32 KB [r][i][c]
    int lc = blockIdx.x / 560;
    int rem = blockIdx.x % 560;
    int nl = rem / KH, k2 = rem % KH;
    const float* Yc = Y + (size_t)lc * CHS + ((size_t)(nl * KH + k2)) * 8192;
    float* Xc = X + (size_t)lc * CHS;
    int t = threadIdx.x;
    float4* yl4 = (float4*)yl;
    const float4* ys4 = (const float4*)Yc;
    for (int e = t; e < 2048; e += 512) yl4[e] = ys4[e];
    __syncthreads();
    int i = t & 63, k1g = t >> 6;
    for (int j = 0; j < 9; ++j) {
        int k1 = k1g + 8 * j;
        if (k1 >= 68) break;
        const float* w = Wf + 2 * (k1 << 6);   // wave-uniform -> broadcast
        float ar = 0.f, ai = 0.f;
        #pragma unroll 16
        for (int r = 0; r < 64; r += 2) {
            float4 wv = *(const float4*)(w + 2 * r);
            float2 z0 = *(const float2*)(yl + (r << 7) + 2 * i);
            float2 z1 = *(const float2*)(yl + ((r + 1) << 7) + 2 * i);
            ar += wv.x * z0.x - wv.y * z0.y;
            ai += wv.x * z0.y + wv.y * z0.x;
            ar += wv.z * z1.x - wv.w * z1.y;
            ai += wv.z * z1.y + wv.w * z1.x;
        }
        *(float2*)(Xc + ((size_t)(nl * 68 + k1) * KH + k2) * 128 + 2 * i)
            = make_float2(ar, ai);
    }
}

// ---------------- stage 3: per-bin channel mix (2o x 2n register tile) -----
// O[nl][k2][k1][o] = sum_i X[nl][k1][k2][i] * K[bin][i][o]
__global__ void k_mix(const float* __restrict__ X, const float* __restrict__ Kt,
                      const float* __restrict__ kr, const float* __restrict__ ki,
                      float* __restrict__ O, int useKt) {
    __shared__ float xl[16 * 128];       // [n][i][c]  8 KB
    __shared__ float kl[64 * 64 * 2];    // [i][o][c] 32 KB
    int lc = blockIdx.x / 2380;
    int bin = blockIdx.x % 2380;
    int k1 = bin / KH, k2 = bin % KH;
    const float* Xc = X + (size_t)lc * CHS;
    float* Oc = O + (size_t)lc * CHS;
    int t = threadIdx.x;
    for (int e = t; e < 2048; e += 256) {
        int n = e >> 7, ic = e & 127;
        xl[e] = Xc[((size_t)(n * 68 + k1) * KH + k2) * 128 + ic];
    }
    if (useKt) {
        const float* src = Kt + (size_t)bin * 8192;
        for (int e = t; e < 8192; e += 256) kl[e] = src[e];
    } else {
        for (int e = t; e < 4096; e += 256) {
            int o = e >> 6, i = e & 63;
            size_t gi = ((size_t)(o * 64 + i) * 68 + k1) * 68 + k2;
            kl[i * 128 + o * 2]     = kr[gi];
            kl[i * 128 + o * 2 + 1] = ki[gi];
        }
    }
    __syncthreads();
    int op = t & 31, g = t >> 5;         // o = 2op,2op+1 ; n = g, g+8
    float a0r=0,a0i=0,a1r=0,a1i=0,b0r=0,b0i=0,b1r=0,b1i=0;
    for (int i = 0; i < 64; ++i) {
        float4 kv = *(const float4*)(kl + i * 128 + op * 4);
        float2 c0 = *(const float2*)(xl + (g << 7) + i * 2);
        float2 c1 = *(const float2*)(xl + ((g + 8) << 7) + i * 2);
        a0r += kv.x * c0.x - kv.y * c0.y;  a0i += kv.x * c0.y + kv.y * c0.x;
        a1r += kv.z * c0.x - kv.w * c0.y;  a1i += kv.z * c0.y + kv.w * c0.x;
        b0r += kv.x * c1.x - kv.y * c1.y;  b0i += kv.x * c1.y + kv.y * c1.x;
        b1r += kv.z * c1.x - kv.w * c1.y;  b1i += kv.z * c1.y + kv.w * c1.x;
    }
    size_t base0 = ((((size_t)g       * KH + k2) * 68 + k1) * 64 + 2 * op) * 2;
    size_t base1 = ((((size_t)(g + 8) * KH + k2) * 68 + k1) * 64 + 2 * op) * 2;
    *(float4*)(Oc + base0) = make_float4(a0r, a0i, a1r, a1i);
    *(float4*)(Oc + base1) = make_float4(b0r, b0i, b1r, b1i);
}

// ---------------- stage 4: inverse column DFT ----------------
// Z[nl][p][k2][o] = sum_k1 Wi[p][k1] * O[nl][k2][k1][o]
__global__ __launch_bounds__(512) void k_inv_col(
        const float* __restrict__ O, const float* __restrict__ Wi,
        float* __restrict__ Z) {
    __shared__ float ol[68 * 128];       // 34 KB
    __shared__ float wih[34 * 136];      // 18.5 KB
    int lc = blockIdx.x / 1120;
    int rem = blockIdx.x % 1120;
    int ph = rem & 1;
    int rest = rem >> 1;
    int k2 = rest % KH, nl = rest / KH;
    int t = threadIdx.x;
    const float* Oc = O + (size_t)lc * CHS;
    float* Zc = Z + (size_t)lc * CHS;
    const float4* osrc = (const float4*)(Oc + ((size_t)nl * KH + k2) * 68 * 128);
    float4* ol4 = (float4*)ol;
    for (int e = t; e < 68 * 32; e += 512) ol4[e] = osrc[e];
    const float* wsrc = Wi + (size_t)ph * 34 * 136;
    for (int e = t; e < 34 * 136; e += 512) wih[e] = wsrc[e];
    __syncthreads();
    int o = t & 63, g = t >> 6;
    const float* oo_ = ol + o * 2;
    for (int j = 0; j < 5; ++j) {
        int pl = g + 8 * j;
        if (pl >= 34) break;
        int p = ph * 34 + pl;
        const float* w = wih + pl * 136;
        float ar = 0.f, ai = 0.f;
        #pragma unroll 17
        for (int k1 = 0; k1 < 68; k1 += 2) {
            float4 wv = *(const float4*)(w + 2 * k1);
            float2 q0 = *(const float2*)(oo_ + k1 * 128);
            float2 q1 = *(const float2*)(oo_ + k1 * 128 + 128);
            ar += wv.x * q0.x - wv.y * q0.y;
            ai += wv.x * q0.y + wv.y * q0.x;
            ar += wv.z * q1.x - wv.w * q1.y;
            ai += wv.z * q1.y + wv.w * q1.x;
        }
        *(float2*)(Zc + ((size_t)(nl * 68 + p) * KH + k2) * 128 + o * 2)
            = make_float2(ar, ai);
    }
}

// ---------------- stage 5: inverse row DFT + direct overlap-add -------------
// out[b, 66*tr+p, 66*tc+q, o] += bias[o] + sum_k2 Re(Z[nl][p][k2][o]*Wg[q][k2])
__global__ __launch_bounds__(256) void k_fused_inv(
        const float* __restrict__ Z, const float* __restrict__ Wg,
        const float* __restrict__ bias, float* __restrict__ out, int c0) {
    __shared__ float zl[KH * 128];       // 17.9 KB
    int lc = blockIdx.x / 1088;
    int rem = blockIdx.x % 1088;
    int nl = rem / 68, p = rem % 68;
    int b = c0 + lc;
    int tr = nl >> 2, tc = nl & 3;
    int y = 66 * tr + p;
    if (y >= 256) return;
    const float4* zs4 = (const float4*)(Z + (size_t)lc * CHS
                                        + ((size_t)(nl * 68 + p)) * 4480);
    int t = threadIdx.x;
    float4* zl4 = (float4*)zl;
    for (int e = t; e < 1120; e += 256) zl4[e] = zs4[e];
    __syncthreads();
    int o = t & 63, qg = t >> 6;
    float bv = bias[o];
    const float* zr = zl + 2 * o;
    float* orow = out + ((size_t)(b * 256 + y)) * 256 * 64 + o;
    for (int q = qg; q < 68; q += 4) {
        int x = 66 * tc + q;
        if (x >= 256) break;
        const float* w = Wg + q * 70;    // wave-uniform -> broadcast
        float acc = bv;
        #pragma unroll 7
        for (int k2 = 0; k2 < KH; ++k2) {
            float2 wv = *(const float2*)(w + 2 * k2);
            float2 zv = *(const float2*)(zr + (k2 << 7));
            acc += zv.x * wv.x - zv.y * wv.y;
        }
        atomicAdd(orow + (size_t)x * 64, acc);
    }
}

extern "C" void kernel_launch(void* const* d_in, const int* in_sizes, int n_in,
                              void* d_out, int out_size, void* d_ws, size_t ws_size,
                              hipStream_t stream) {
    const float* x    = (const float*)d_in[0];
    const float* kr   = (const float*)d_in[1];
    const float* ki   = (const float*)d_in[2];
    const float* bias = (const float*)d_in[3];
    float* out = (float*)d_out;
    float* ws  = (float*)d_ws;

    int useKt = 1;
    int CH = 8;
    while (CH > 1 && (22720ull + KT_FLOATS + 2ull * CH * CHS) * 4ull > ws_size) CH >>= 1;
    if ((22720ull + KT_FLOATS + 2ull * CH * CHS) * 4ull > ws_size) {
        useKt = 0;
        CH = 8;
        while (CH > 1 && (22720ull + 2ull * CH * CHS) * 4ull > ws_size) CH >>= 1;
    }

    float* Wf   = ws;                          // 8704 floats
    float* Wi   = ws + 8704;                   // 9248 floats
    float* Wg   = ws + 17952;                  // 4760 floats
    float* Kt   = ws + 22720;                  // KT_FLOATS (if useKt)
    float* bufA = Kt + (useKt ? KT_FLOATS : 0);   // Y then O
    float* bufB = bufA + (size_t)CH * CHS;        // X then Z

    k_twiddle<<<1, 256, 0, stream>>>(ws);
    if (useKt)
        k_ktrans<<<68 * 64, 256, 0, stream>>>(kr, ki, Kt);
    k_zero<<<2048, 256, 0, stream>>>(out, 8 * 256 * 256 * 64);

    for (int s = 0; s < 8; s += CH) {
        k_fwd_row<<<CH * 1024, 256, 0, stream>>>(x, Wf, bufA, s);
        k_fwd_col<<<CH * 560, 512, 0, stream>>>(bufA, Wf, bufB);
        k_mix<<<CH * 2380, 256, 0, stream>>>(bufB, Kt, kr, ki, bufA, useKt);
        k_inv_col<<<CH * 1120, 512, 0, stream>>>(bufA, Wi, bufB);
        k_fused_inv<<<CH * 1088, 256, 0, stream>>>(bufB, Wg, bias, out, s);
    }
}

// Round 8
// 1532.752 us; speedup vs baseline: 1.0374x; 1.0374x over previous
//
#include <hip/hip_runtime.h>
#include <hip/hip_bf16.h>

// FFT-tiled conv: B=8, IMG=256, CIN=COUT=64, TILE=64, FFT=68, PAD=2.
// Frequency-domain per-tile conv via DFT-as-matmul, Hermitian half-spectrum
// (k2 in [0,35)), direct overlap-add: plain stores for owned pixels,
// atomics only on tile seams (~11% of pixels). All fp32.
//
// Layouts (per 16-tile chunk slot of CHS floats):
//   Y  [nl][k2][r][i][c]      in bufA     ((nl*35+k2)*64+r)*128
//   X  [nl][k1][k2][i][c]     in bufB     ((nl*68+k1)*35+k2)*128
//   K_t[bin][i][o][c]         78 MB, one-time (bin = k1*35+k2)
//   O  [nl][k2][k1][o][c]     in bufA     ((nl*35+k2)*68+k1)*128
//   Z  [nl][p][k2][o][c]      in bufB     ((nl*68+p)*35+k2)*128

#define KH   35
#define CHS  4874240ull                       // floats per chunk slot
#define KT_FLOATS (68ull * KH * 64 * 64 * 2)  // 19,496,960

__global__ void k_twiddle(float* ws) {
    const float TWO_PI = 6.28318530717958647692f;
    int t = threadIdx.x;
    float* Wf = ws;
    for (int e = t; e < 68 * 64; e += 256) {
        int k = e >> 6, m = e & 63;
        int ph = (k * (m + 2)) % 68;
        float a = TWO_PI * (float)ph / 68.0f;
        Wf[2 * e]     = cosf(a);
        Wf[2 * e + 1] = -sinf(a);
    }
    float* Wi = ws + 8704;
    for (int e = t; e < 68 * 68; e += 256) {
        int p = e / 68, k = e % 68;
        int ph = (p * k) % 68;
        float a = TWO_PI * (float)ph / 68.0f;
        Wi[2 * e]     = cosf(a) / 68.0f;
        Wi[2 * e + 1] = sinf(a) / 68.0f;
    }
    float* Wg = ws + 17952;
    for (int e = t; e < 68 * KH; e += 256) {
        int q = e / KH, k2 = e % KH;
        int ph = (q * k2) % 68;
        float a = TWO_PI * (float)ph / 68.0f;
        float alpha = (k2 == 0 || k2 == 34) ? 1.0f : 2.0f;
        Wg[2 * e]     = alpha * cosf(a) / 68.0f;
        Wg[2 * e + 1] = alpha * sinf(a) / 68.0f;
    }
}

__global__ void k_zero(float* out, int n) {
    int idx = blockIdx.x * 256 + threadIdx.x;
    float4* o4 = (float4*)out;
    for (int i = idx; i < n / 4; i += gridDim.x * 256) o4[i] = make_float4(0, 0, 0, 0);
}

// ---------- one-time kernel-spectrum transpose: K_t[bin][i][o][c] ----------
__global__ void k_ktrans(const float* __restrict__ kr, const float* __restrict__ ki,
                         float* __restrict__ Kt) {
    __shared__ float tr[64 * 37];
    __shared__ float ti[64 * 37];
    int k1 = blockIdx.x >> 6, i = blockIdx.x & 63;
    int t = threadIdx.x;
    for (int e = t; e < 64 * KH; e += 256) {
        int o = e / KH, k2 = e % KH;
        size_t src = ((size_t)(o * 64 + i) * 68 + k1) * 68 + k2;
        tr[o * 37 + k2] = kr[src];
        ti[o * 37 + k2] = ki[src];
    }
    __syncthreads();
    for (int e = t; e < KH * 64; e += 256) {
        int k2 = e >> 6, o = e & 63;
        size_t dst = ((size_t)(k1 * KH + k2)) * 8192 + (size_t)i * 128 + o * 2;
        Kt[dst]     = tr[o * 37 + k2];
        Kt[dst + 1] = ti[o * 37 + k2];
    }
}

// ---------------- stage 1: row DFT ----------------
// Y[nl][k2][r][i] = sum_c x[b, tr*64+r, tc*64+c, i] * Wf[k2][c]
__global__ void k_fwd_row(const float* __restrict__ x, const float* __restrict__ Wf,
                          float* __restrict__ Y, int c0) {
    __shared__ float xr[64 * 64];        // [c][i]
    __shared__ float wf[KH * 64 * 2];    // [k2][c]
    __shared__ float yout[KH * 128];     // [k2][i][c]
    int lc = blockIdx.x >> 10;
    int rem = blockIdx.x & 1023;
    int nl = rem >> 6, r = rem & 63;
    int n = (c0 + lc) * 16 + nl;
    int b = n >> 4, tr = (n >> 2) & 3, tc = n & 3;
    const float* src = x + (((size_t)(b * 256 + tr * 64 + r)) * 256 + tc * 64) * 64;
    int t = threadIdx.x;
    const float4* src4 = (const float4*)src;
    float4* xr4 = (float4*)xr;
    for (int e = t; e < 1024; e += 256) xr4[e] = src4[e];
    for (int e = t; e < KH * 64 * 2; e += 256) wf[e] = Wf[e];
    __syncthreads();
    int i = t & 63, kg = t >> 6;
    for (int k2 = kg; k2 < KH; k2 += 4) {
        float ar = 0.f, ai = 0.f;
        const float* w = wf + k2 * 128;
        for (int c = 0; c < 64; ++c) {
            float v = xr[(c << 6) | i];
            ar += v * w[2 * c];
            ai += v * w[2 * c + 1];
        }
        yout[(k2 << 7) + 2 * i]     = ar;
        yout[(k2 << 7) + 2 * i + 1] = ai;
    }
    __syncthreads();
    float* Yc = Y + (size_t)lc * CHS;
    const float4* ys4 = (const float4*)yout;
    for (int e = t; e < KH * 32; e += 256) {
        int k2 = e >> 5, f = e & 31;
        ((float4*)(Yc + ((size_t)(nl * KH + k2) * 64 + r) * 128))[f] = ys4[e];
    }
}

// ---------------- stage 2: column DFT (per-(nl,k2) GEMM) ----------------
// X[nl][k1][k2][i] = sum_r Wf[k1][r] * Y[nl][k2][r][i]
__global__ __launch_bounds__(512) void k_fwd_col(
        const float* __restrict__ Y, const float* __restrict__ Wf,
        float* __restrict__ X) {
    __shared__ float yl[64 * 128];       // 32 KB [r][i][c]
    int lc = blockIdx.x / 560;
    int rem = blockIdx.x % 560;
    int nl = rem / KH, k2 = rem % KH;
    const float* Yc = Y + (size_t)lc * CHS + ((size_t)(nl * KH + k2)) * 8192;
    float* Xc = X + (size_t)lc * CHS;
    int t = threadIdx.x;
    float4* yl4 = (float4*)yl;
    const float4* ys4 = (const float4*)Yc;
    for (int e = t; e < 2048; e += 512) yl4[e] = ys4[e];
    __syncthreads();
    int i = t & 63, k1g = t >> 6;
    for (int j = 0; j < 9; ++j) {
        int k1 = k1g + 8 * j;
        if (k1 >= 68) break;
        const float* w = Wf + 2 * (k1 << 6);   // wave-uniform -> broadcast
        float ar = 0.f, ai = 0.f;
        #pragma unroll 16
        for (int r = 0; r < 64; r += 2) {
            float4 wv = *(const float4*)(w + 2 * r);
            float2 z0 = *(const float2*)(yl + (r << 7) + 2 * i);
            float2 z1 = *(const float2*)(yl + ((r + 1) << 7) + 2 * i);
            ar += wv.x * z0.x - wv.y * z0.y;
            ai += wv.x * z0.y + wv.y * z0.x;
            ar += wv.z * z1.x - wv.w * z1.y;
            ai += wv.z * z1.y + wv.w * z1.x;
        }
        *(float2*)(Xc + ((size_t)(nl * 68 + k1) * KH + k2) * 128 + 2 * i)
            = make_float2(ar, ai);
    }
}

// ---------------- stage 3: per-bin channel mix (2o x 2n register tile) -----
// O[nl][k2][k1][o] = sum_i X[nl][k1][k2][i] * K[bin][i][o]
__global__ void k_mix(const float* __restrict__ X, const float* __restrict__ Kt,
                      const float* __restrict__ kr, const float* __restrict__ ki,
                      float* __restrict__ O, int useKt) {
    __shared__ float xl[16 * 128];       // [n][i][c]  8 KB
    __shared__ float kl[64 * 64 * 2];    // [i][o][c] 32 KB
    int lc = blockIdx.x / 2380;
    int bin = blockIdx.x % 2380;
    int k1 = bin / KH, k2 = bin % KH;
    const float* Xc = X + (size_t)lc * CHS;
    float* Oc = O + (size_t)lc * CHS;
    int t = threadIdx.x;
    for (int e = t; e < 2048; e += 256) {
        int n = e >> 7, ic = e & 127;
        xl[e] = Xc[((size_t)(n * 68 + k1) * KH + k2) * 128 + ic];
    }
    if (useKt) {
        const float* src = Kt + (size_t)bin * 8192;
        for (int e = t; e < 8192; e += 256) kl[e] = src[e];
    } else {
        for (int e = t; e < 4096; e += 256) {
            int o = e >> 6, i = e & 63;
            size_t gi = ((size_t)(o * 64 + i) * 68 + k1) * 68 + k2;
            kl[i * 128 + o * 2]     = kr[gi];
            kl[i * 128 + o * 2 + 1] = ki[gi];
        }
    }
    __syncthreads();
    int op = t & 31, g = t >> 5;         // o = 2op,2op+1 ; n = g, g+8
    float a0r=0,a0i=0,a1r=0,a1i=0,b0r=0,b0i=0,b1r=0,b1i=0;
    for (int i = 0; i < 64; ++i) {
        float4 kv = *(const float4*)(kl + i * 128 + op * 4);
        float2 c0 = *(const float2*)(xl + (g << 7) + i * 2);
        float2 c1 = *(const float2*)(xl + ((g + 8) << 7) + i * 2);
        a0r += kv.x * c0.x - kv.y * c0.y;  a0i += kv.x * c0.y + kv.y * c0.x;
        a1r += kv.z * c0.x - kv.w * c0.y;  a1i += kv.z * c0.y + kv.w * c0.x;
        b0r += kv.x * c1.x - kv.y * c1.y;  b0i += kv.x * c1.y + kv.y * c1.x;
        b1r += kv.z * c1.x - kv.w * c1.y;  b1i += kv.z * c1.y + kv.w * c1.x;
    }
    size_t base0 = ((((size_t)g       * KH + k2) * 68 + k1) * 64 + 2 * op) * 2;
    size_t base1 = ((((size_t)(g + 8) * KH + k2) * 68 + k1) * 64 + 2 * op) * 2;
    *(float4*)(Oc + base0) = make_float4(a0r, a0i, a1r, a1i);
    *(float4*)(Oc + base1) = make_float4(b0r, b0i, b1r, b1i);
}

// ---------------- stage 4: inverse column DFT ----------------
// Z[nl][p][k2][o] = sum_k1 Wi[p][k1] * O[nl][k2][k1][o]
__global__ __launch_bounds__(512) void k_inv_col(
        const float* __restrict__ O, const float* __restrict__ Wi,
        float* __restrict__ Z) {
    __shared__ float ol[68 * 128];       // 34 KB
    __shared__ float wih[34 * 136];      // 18.5 KB
    int lc = blockIdx.x / 1120;
    int rem = blockIdx.x % 1120;
    int ph = rem & 1;
    int rest = rem >> 1;
    int k2 = rest % KH, nl = rest / KH;
    int t = threadIdx.x;
    const float* Oc = O + (size_t)lc * CHS;
    float* Zc = Z + (size_t)lc * CHS;
    const float4* osrc = (const float4*)(Oc + ((size_t)nl * KH + k2) * 68 * 128);
    float4* ol4 = (float4*)ol;
    for (int e = t; e < 68 * 32; e += 512) ol4[e] = osrc[e];
    const float* wsrc = Wi + (size_t)ph * 34 * 136;
    for (int e = t; e < 34 * 136; e += 512) wih[e] = wsrc[e];
    __syncthreads();
    int o = t & 63, g = t >> 6;
    const float* oo_ = ol + o * 2;
    for (int j = 0; j < 5; ++j) {
        int pl = g + 8 * j;
        if (pl >= 34) break;
        int p = ph * 34 + pl;
        const float* w = wih + pl * 136;
        float ar = 0.f, ai = 0.f;
        #pragma unroll 17
        for (int k1 = 0; k1 < 68; k1 += 2) {
            float4 wv = *(const float4*)(w + 2 * k1);
            float2 q0 = *(const float2*)(oo_ + k1 * 128);
            float2 q1 = *(const float2*)(oo_ + k1 * 128 + 128);
            ar += wv.x * q0.x - wv.y * q0.y;
            ai += wv.x * q0.y + wv.y * q0.x;
            ar += wv.z * q1.x - wv.w * q1.y;
            ai += wv.z * q1.y + wv.w * q1.x;
        }
        *(float2*)(Zc + ((size_t)(nl * 68 + p) * KH + k2) * 128 + o * 2)
            = make_float2(ar, ai);
    }
}

// ---------------- stage 5: inverse row DFT + overlap-add --------------------
// out[b, 66*tr+p, 66*tc+q, o] (+)= bias[o] + sum_k2 Re(Z[nl][p][k2][o]*Wg[q][k2])
// Interior pixels (unique contributor): plain store. Seam pixels: atomicAdd.
__global__ __launch_bounds__(256) void k_fused_inv(
        const float* __restrict__ Z, const float* __restrict__ Wg,
        const float* __restrict__ bias, float* __restrict__ out, int c0) {
    __shared__ float zl[KH * 128];       // 17.9 KB
    int lc = blockIdx.x / 1088;
    int rem = blockIdx.x % 1088;
    int nl = rem / 68, p = rem % 68;
    int b = c0 + lc;
    int tr = nl >> 2, tc = nl & 3;
    int y = 66 * tr + p;
    if (y >= 256) return;
    const float4* zs4 = (const float4*)(Z + (size_t)lc * CHS
                                        + ((size_t)(nl * 68 + p)) * 4480);
    int t = threadIdx.x;
    float4* zl4 = (float4*)zl;
    for (int e = t; e < 1120; e += 256) zl4[e] = zs4[e];
    __syncthreads();
    int o = t & 63, qg = t >> 6;
    float bv = bias[o];
    const float* zr = zl + 2 * o;
    float* orow = out + ((size_t)(b * 256 + y)) * 256 * 64 + o;
    bool rowu = !((p <= 1 && tr > 0) || (p >= 66 && tr < 3));
    for (int q = qg; q < 68; q += 4) {
        int x = 66 * tc + q;
        if (x >= 256) break;
        const float* w = Wg + q * 70;    // wave-uniform -> broadcast
        float acc = bv;
        #pragma unroll 7
        for (int k2 = 0; k2 < KH; ++k2) {
            float2 wv = *(const float2*)(w + 2 * k2);
            float2 zv = *(const float2*)(zr + (k2 << 7));
            acc += zv.x * wv.x - zv.y * wv.y;
        }
        bool colu = !((q <= 1 && tc > 0) || (q >= 66 && tc < 3));
        if (rowu && colu) orow[(size_t)x * 64] = acc;
        else              atomicAdd(orow + (size_t)x * 64, acc);
    }
}

extern "C" void kernel_launch(void* const* d_in, const int* in_sizes, int n_in,
                              void* d_out, int out_size, void* d_ws, size_t ws_size,
                              hipStream_t stream) {
    const float* x    = (const float*)d_in[0];
    const float* kr   = (const float*)d_in[1];
    const float* ki   = (const float*)d_in[2];
    const float* bias = (const float*)d_in[3];
    float* out = (float*)d_out;
    float* ws  = (float*)d_ws;

    int useKt = 1;
    int CH = 8;
    while (CH > 1 && (22720ull + KT_FLOATS + 2ull * CH * CHS) * 4ull > ws_size) CH >>= 1;
    if ((22720ull + KT_FLOATS + 2ull * CH * CHS) * 4ull > ws_size) {
        useKt = 0;
        CH = 8;
        while (CH > 1 && (22720ull + 2ull * CH * CHS) * 4ull > ws_size) CH >>= 1;
    }

    float* Wf   = ws;                          // 8704 floats
    float* Wi   = ws + 8704;                   // 9248 floats
    float* Wg   = ws + 17952;                  // 4760 floats
    float* Kt   = ws + 22720;                  // KT_FLOATS (if useKt)
    float* bufA = Kt + (useKt ? KT_FLOATS : 0);   // Y then O
    float* bufB = bufA + (size_t)CH * CHS;        // X then Z

    k_twiddle<<<1, 256, 0, stream>>>(ws);
    if (useKt)
        k_ktrans<<<68 * 64, 256, 0, stream>>>(kr, ki, Kt);
    k_zero<<<2048, 256, 0, stream>>>(out, 8 * 256 * 256 * 64);

    for (int s = 0; s < 8; s += CH) {
        k_fwd_row<<<CH * 1024, 256, 0, stream>>>(x, Wf, bufA, s);
        k_fwd_col<<<CH * 560, 512, 0, stream>>>(bufA, Wf, bufB);
        k_mix<<<CH * 2380, 256, 0, stream>>>(bufB, Kt, kr, ki, bufA, useKt);
        k_inv_col<<<CH * 1120, 512, 0, stream>>>(bufA, Wi, bufB);
        k_fused_inv<<<CH * 1088, 256, 0, stream>>>(bufB, Wg, bias, out, s);
    }
}

// Round 9
// 1357.004 us; speedup vs baseline: 1.1718x; 1.1295x over previous
//
#include <hip/hip_runtime.h>
#include <hip/hip_bf16.h>

// FFT-tiled conv: B=8, IMG=256, CIN=COUT=64, TILE=64, FFT=68, PAD=2.
// Frequency-domain per-tile conv via DFT-as-matmul, Hermitian half-spectrum
// (k2 in [0,35)), direct overlap-add: plain stores for owned pixels,
// atomics only on tile seams. All fp32.
//
// Layouts (per 16-tile chunk slot of CHS floats):
//   Y  [nl][k2][r][i][c]      in bufA     ((nl*35+k2)*64+r)*128
//   X  [nl][k1][k2][i][c]     in bufB     ((nl*68+k1)*35+k2)*128
//   K_t[bin][i][o][c]         78 MB, one-time (bin = k1*35+k2)
//   O  [nl][k2][k1][o][c]     in bufA     ((nl*35+k2)*68+k1)*128
//   Z  [nl][p][k2][o][c]      in bufB     ((nl*68+p)*35+k2)*128

#define KH   35
#define CHS  4874240ull                       // floats per chunk slot
#define KT_FLOATS (68ull * KH * 64 * 64 * 2)  // 19,496,960

__global__ void k_twiddle(float* ws) {
    const float TWO_PI = 6.28318530717958647692f;
    int t = threadIdx.x;
    float* Wf = ws;
    for (int e = t; e < 68 * 64; e += 256) {
        int k = e >> 6, m = e & 63;
        int ph = (k * (m + 2)) % 68;
        float a = TWO_PI * (float)ph / 68.0f;
        Wf[2 * e]     = cosf(a);
        Wf[2 * e + 1] = -sinf(a);
    }
    float* Wi = ws + 8704;
    for (int e = t; e < 68 * 68; e += 256) {
        int p = e / 68, k = e % 68;
        int ph = (p * k) % 68;
        float a = TWO_PI * (float)ph / 68.0f;
        Wi[2 * e]     = cosf(a) / 68.0f;
        Wi[2 * e + 1] = sinf(a) / 68.0f;
    }
    float* Wg = ws + 17952;
    for (int e = t; e < 68 * KH; e += 256) {
        int q = e / KH, k2 = e % KH;
        int ph = (q * k2) % 68;
        float a = TWO_PI * (float)ph / 68.0f;
        float alpha = (k2 == 0 || k2 == 34) ? 1.0f : 2.0f;
        Wg[2 * e]     = alpha * cosf(a) / 68.0f;
        Wg[2 * e + 1] = alpha * sinf(a) / 68.0f;
    }
}

__global__ void k_zero(float* out, int n) {
    int idx = blockIdx.x * 256 + threadIdx.x;
    float4* o4 = (float4*)out;
    for (int i = idx; i < n / 4; i += gridDim.x * 256) o4[i] = make_float4(0, 0, 0, 0);
}

// ---------- one-time kernel-spectrum transpose: K_t[bin][i][o][c] ----------
__global__ void k_ktrans(const float* __restrict__ kr, const float* __restrict__ ki,
                         float* __restrict__ Kt) {
    __shared__ float tr[64 * 37];
    __shared__ float ti[64 * 37];
    int k1 = blockIdx.x >> 6, i = blockIdx.x & 63;
    int t = threadIdx.x;
    for (int e = t; e < 64 * KH; e += 256) {
        int o = e / KH, k2 = e % KH;
        size_t src = ((size_t)(o * 64 + i) * 68 + k1) * 68 + k2;
        tr[o * 37 + k2] = kr[src];
        ti[o * 37 + k2] = ki[src];
    }
    __syncthreads();
    for (int e = t; e < KH * 64; e += 256) {
        int k2 = e >> 6, o = e & 63;
        size_t dst = ((size_t)(k1 * KH + k2)) * 8192 + (size_t)i * 128 + o * 2;
        Kt[dst]     = tr[o * 37 + k2];
        Kt[dst + 1] = ti[o * 37 + k2];
    }
}

// ---------------- stage 1: row DFT ----------------
// Y[nl][k2][r][i] = sum_c x[b, tr*64+r, tc*64+c, i] * Wf[k2][c]
__global__ void k_fwd_row(const float* __restrict__ x, const float* __restrict__ Wf,
                          float* __restrict__ Y, int c0) {
    __shared__ float xr[64 * 64];        // [c][i]
    __shared__ float wf[KH * 64 * 2];    // [k2][c]
    __shared__ float yout[KH * 128];     // [k2][i][c]
    int lc = blockIdx.x >> 10;
    int rem = blockIdx.x & 1023;
    int nl = rem >> 6, r = rem & 63;
    int n = (c0 + lc) * 16 + nl;
    int b = n >> 4, tr = (n >> 2) & 3, tc = n & 3;
    const float* src = x + (((size_t)(b * 256 + tr * 64 + r)) * 256 + tc * 64) * 64;
    int t = threadIdx.x;
    const float4* src4 = (const float4*)src;
    float4* xr4 = (float4*)xr;
    for (int e = t; e < 1024; e += 256) xr4[e] = src4[e];
    for (int e = t; e < KH * 64 * 2; e += 256) wf[e] = Wf[e];
    __syncthreads();
    int i = t & 63, kg = t >> 6;
    for (int k2 = kg; k2 < KH; k2 += 4) {
        float ar = 0.f, ai = 0.f;
        const float* w = wf + k2 * 128;
        for (int c = 0; c < 64; ++c) {
            float v = xr[(c << 6) | i];
            ar += v * w[2 * c];
            ai += v * w[2 * c + 1];
        }
        yout[(k2 << 7) + 2 * i]     = ar;
        yout[(k2 << 7) + 2 * i + 1] = ai;
    }
    __syncthreads();
    float* Yc = Y + (size_t)lc * CHS;
    const float4* ys4 = (const float4*)yout;
    for (int e = t; e < KH * 32; e += 256) {
        int k2 = e >> 5, f = e & 31;
        ((float4*)(Yc + ((size_t)(nl * KH + k2) * 64 + r) * 128))[f] = ys4[e];
    }
}

// ---------------- stage 2: column DFT (per-(nl,k2) GEMM) ----------------
// X[nl][k1][k2][i] = sum_r Wf[k1][r] * Y[nl][k2][r][i]
__global__ __launch_bounds__(512) void k_fwd_col(
        const float* __restrict__ Y, const float* __restrict__ Wf,
        float* __restrict__ X) {
    __shared__ float yl[64 * 128];       // 32 KB [r][i][c]
    int lc = blockIdx.x / 560;
    int rem = blockIdx.x % 560;
    int nl = rem / KH, k2 = rem % KH;
    const float* Yc = Y + (size_t)lc * CHS + ((size_t)(nl * KH + k2)) * 8192;
    float* Xc = X + (size_t)lc * CHS;
    int t = threadIdx.x;
    float4* yl4 = (float4*)yl;
    const float4* ys4 = (const float4*)Yc;
    for (int e = t; e < 2048; e += 512) yl4[e] = ys4[e];
    __syncthreads();
    int i = t & 63, k1g = t >> 6;
    for (int j = 0; j < 9; ++j) {
        int k1 = k1g + 8 * j;
        if (k1 >= 68) break;
        const float* w = Wf + 2 * (k1 << 6);   // wave-uniform -> broadcast
        float ar = 0.f, ai = 0.f;
        #pragma unroll 16
        for (int r = 0; r < 64; r += 2) {
            float4 wv = *(const float4*)(w + 2 * r);
            float2 z0 = *(const float2*)(yl + (r << 7) + 2 * i);
            float2 z1 = *(const float2*)(yl + ((r + 1) << 7) + 2 * i);
            ar += wv.x * z0.x - wv.y * z0.y;
            ai += wv.x * z0.y + wv.y * z0.x;
            ar += wv.z * z1.x - wv.w * z1.y;
            ai += wv.z * z1.y + wv.w * z1.x;
        }
        *(float2*)(Xc + ((size_t)(nl * 68 + k1) * KH + k2) * 128 + 2 * i)
            = make_float2(ar, ai);
    }
}

// ---------------- stage 3: per-bin channel mix (2o x 2n register tile) -----
// O[nl][k2][k1][o] = sum_i X[nl][k1][k2][i] * K[bin][i][o]
__global__ void k_mix(const float* __restrict__ X, const float* __restrict__ Kt,
                      const float* __restrict__ kr, const float* __restrict__ ki,
                      float* __restrict__ O, int useKt) {
    __shared__ float xl[16 * 128];       // [n][i][c]  8 KB
    __shared__ float kl[64 * 64 * 2];    // [i][o][c] 32 KB
    int lc = blockIdx.x / 2380;
    int bin = blockIdx.x % 2380;
    int k1 = bin / KH, k2 = bin % KH;
    const float* Xc = X + (size_t)lc * CHS;
    float* Oc = O + (size_t)lc * CHS;
    int t = threadIdx.x;
    for (int e = t; e < 2048; e += 256) {
        int n = e >> 7, ic = e & 127;
        xl[e] = Xc[((size_t)(n * 68 + k1) * KH + k2) * 128 + ic];
    }
    if (useKt) {
        const float* src = Kt + (size_t)bin * 8192;
        for (int e = t; e < 8192; e += 256) kl[e] = src[e];
    } else {
        for (int e = t; e < 4096; e += 256) {
            int o = e >> 6, i = e & 63;
            size_t gi = ((size_t)(o * 64 + i) * 68 + k1) * 68 + k2;
            kl[i * 128 + o * 2]     = kr[gi];
            kl[i * 128 + o * 2 + 1] = ki[gi];
        }
    }
    __syncthreads();
    int op = t & 31, g = t >> 5;         // o = 2op,2op+1 ; n = g, g+8
    float a0r=0,a0i=0,a1r=0,a1i=0,b0r=0,b0i=0,b1r=0,b1i=0;
    for (int i = 0; i < 64; ++i) {
        float4 kv = *(const float4*)(kl + i * 128 + op * 4);
        float2 c0 = *(const float2*)(xl + (g << 7) + i * 2);
        float2 c1 = *(const float2*)(xl + ((g + 8) << 7) + i * 2);
        a0r += kv.x * c0.x - kv.y * c0.y;  a0i += kv.x * c0.y + kv.y * c0.x;
        a1r += kv.z * c0.x - kv.w * c0.y;  a1i += kv.z * c0.y + kv.w * c0.x;
        b0r += kv.x * c1.x - kv.y * c1.y;  b0i += kv.x * c1.y + kv.y * c1.x;
        b1r += kv.z * c1.x - kv.w * c1.y;  b1i += kv.z * c1.y + kv.w * c1.x;
    }
    size_t base0 = ((((size_t)g       * KH + k2) * 68 + k1) * 64 + 2 * op) * 2;
    size_t base1 = ((((size_t)(g + 8) * KH + k2) * 68 + k1) * 64 + 2 * op) * 2;
    *(float4*)(Oc + base0) = make_float4(a0r, a0i, a1r, a1i);
    *(float4*)(Oc + base1) = make_float4(b0r, b0i, b1r, b1i);
}

// ---------------- stage 4: inverse column DFT ----------------
// Z[nl][p][k2][o] = sum_k1 Wi[p][k1] * O[nl][k2][k1][o]
__global__ __launch_bounds__(512) void k_inv_col(
        const float* __restrict__ O, const float* __restrict__ Wi,
        float* __restrict__ Z) {
    __shared__ float ol[68 * 128];       // 34 KB
    __shared__ float wih[34 * 136];      // 18.5 KB
    int lc = blockIdx.x / 1120;
    int rem = blockIdx.x % 1120;
    int ph = rem & 1;
    int rest = rem >> 1;
    int k2 = rest % KH, nl = rest / KH;
    int t = threadIdx.x;
    const float* Oc = O + (size_t)lc * CHS;
    float* Zc = Z + (size_t)lc * CHS;
    const float4* osrc = (const float4*)(Oc + ((size_t)nl * KH + k2) * 68 * 128);
    float4* ol4 = (float4*)ol;
    for (int e = t; e < 68 * 32; e += 512) ol4[e] = osrc[e];
    const float* wsrc = Wi + (size_t)ph * 34 * 136;
    for (int e = t; e < 34 * 136; e += 512) wih[e] = wsrc[e];
    __syncthreads();
    int o = t & 63, g = t >> 6;
    const float* oo_ = ol + o * 2;
    for (int j = 0; j < 5; ++j) {
        int pl = g + 8 * j;
        if (pl >= 34) break;
        int p = ph * 34 + pl;
        const float* w = wih + pl * 136;
        float ar = 0.f, ai = 0.f;
        #pragma unroll 17
        for (int k1 = 0; k1 < 68; k1 += 2) {
            float4 wv = *(const float4*)(w + 2 * k1);
            float2 q0 = *(const float2*)(oo_ + k1 * 128);
            float2 q1 = *(const float2*)(oo_ + k1 * 128 + 128);
            ar += wv.x * q0.x - wv.y * q0.y;
            ai += wv.x * q0.y + wv.y * q0.x;
            ar += wv.z * q1.x - wv.w * q1.y;
            ai += wv.z * q1.y + wv.w * q1.x;
        }
        *(float2*)(Zc + ((size_t)(nl * 68 + p) * KH + k2) * 128 + o * 2)
            = make_float2(ar, ai);
    }
}

// ---------------- stage 5: inverse row DFT + overlap-add --------------------
// out[b, 66*tr+p, 66*tc+q, o] (+)= bias[o] + sum_k2 Re(Z[nl][p][k2][o]*Wg[q][k2])
// q register-blocked: 17 independent accumulators per thread, one zv LDS read
// per k2 (17x reuse), Wg staged in LDS (broadcast reads). Interior pixels:
// plain store; seam pixels: atomicAdd.
__global__ __launch_bounds__(256) void k_fused_inv(
        const float* __restrict__ Z, const float* __restrict__ Wg,
        const float* __restrict__ bias, float* __restrict__ out, int c0) {
    __shared__ float zl[KH * 128];       // 17.9 KB [k2][o][c]
    __shared__ float wg[68 * 70];        // 19.0 KB [q][k2c]
    int lc = blockIdx.x / 1088;
    int rem = blockIdx.x % 1088;
    int nl = rem / 68, p = rem % 68;
    int b = c0 + lc;
    int tr = nl >> 2, tc = nl & 3;
    int y = 66 * tr + p;
    if (y >= 256) return;
    int t = threadIdx.x;
    const float4* zs4 = (const float4*)(Z + (size_t)lc * CHS
                                        + ((size_t)(nl * 68 + p)) * 4480);
    float4* zl4 = (float4*)zl;
    for (int e = t; e < 1120; e += 256) zl4[e] = zs4[e];
    for (int e = t; e < 4760; e += 256) wg[e] = Wg[e];
    __syncthreads();

    int o = t & 63, qg = t >> 6;         // qg in 0..3, q = qg*17 + j
    float bv = bias[o];
    const float* zr = zl + 2 * o;
    const float* wbase = wg + (qg * 17) * 70;

    float acc[17];
    #pragma unroll
    for (int j = 0; j < 17; ++j) acc[j] = 0.f;

    for (int k2 = 0; k2 < KH; ++k2) {
        float2 zv = *(const float2*)(zr + (k2 << 7));
        #pragma unroll
        for (int j = 0; j < 17; ++j) {
            float2 wv = *(const float2*)(wbase + j * 70 + 2 * k2);  // broadcast
            acc[j] += zv.x * wv.x - zv.y * wv.y;
        }
    }

    bool rowu = !((p <= 1 && tr > 0) || (p >= 66 && tr < 3));
    float* orow = out + ((size_t)(b * 256 + y)) * 256 * 64 + o;
    #pragma unroll
    for (int j = 0; j < 17; ++j) {
        int q = qg * 17 + j;
        int x = 66 * tc + q;
        if (x >= 256) continue;
        bool colu = !((q <= 1 && tc > 0) || (q >= 66 && tc < 3));
        float v = acc[j] + bv;
        if (rowu && colu) orow[(size_t)x * 64] = v;
        else              atomicAdd(orow + (size_t)x * 64, v);
    }
}

extern "C" void kernel_launch(void* const* d_in, const int* in_sizes, int n_in,
                              void* d_out, int out_size, void* d_ws, size_t ws_size,
                              hipStream_t stream) {
    const float* x    = (const float*)d_in[0];
    const float* kr   = (const float*)d_in[1];
    const float* ki   = (const float*)d_in[2];
    const float* bias = (const float*)d_in[3];
    float* out = (float*)d_out;
    float* ws  = (float*)d_ws;

    int useKt = 1;
    int CH = 8;
    while (CH > 1 && (22720ull + KT_FLOATS + 2ull * CH * CHS) * 4ull > ws_size) CH >>= 1;
    if ((22720ull + KT_FLOATS + 2ull * CH * CHS) * 4ull > ws_size) {
        useKt = 0;
        CH = 8;
        while (CH > 1 && (22720ull + 2ull * CH * CHS) * 4ull > ws_size) CH >>= 1;
    }

    float* Wf   = ws;                          // 8704 floats
    float* Wi   = ws + 8704;                   // 9248 floats
    float* Wg   = ws + 17952;                  // 4760 floats
    float* Kt   = ws + 22720;                  // KT_FLOATS (if useKt)
    float* bufA = Kt + (useKt ? KT_FLOATS : 0);   // Y then O
    float* bufB = bufA + (size_t)CH * CHS;        // X then Z

    k_twiddle<<<1, 256, 0, stream>>>(ws);
    if (useKt)
        k_ktrans<<<68 * 64, 256, 0, stream>>>(kr, ki, Kt);
    k_zero<<<2048, 256, 0, stream>>>(out, 8 * 256 * 256 * 64);

    for (int s = 0; s < 8; s += CH) {
        k_fwd_row<<<CH * 1024, 256, 0, stream>>>(x, Wf, bufA, s);
        k_fwd_col<<<CH * 560, 512, 0, stream>>>(bufA, Wf, bufB);
        k_mix<<<CH * 2380, 256, 0, stream>>>(bufB, Kt, kr, ki, bufA, useKt);
        k_inv_col<<<CH * 1120, 512, 0, stream>>>(bufA, Wi, bufB);
        k_fused_inv<<<CH * 1088, 256, 0, stream>>>(bufB, Wg, bias, out, s);
    }
}